// Round 5
// baseline (174.846 us; speedup 1.0000x reference)
//
#include <hip/hip_runtime.h>
#include <hip/hip_cooperative_groups.h>

namespace cg = cooperative_groups;

// Problem constants (from reference)
#define NB 4
#define NN 20000
#define NE 320000
#define HH 128

#define NBLK 256          // 1 block/CU -> cooperative co-residency guaranteed
#define NTHR 512          // 8 waves/block
#define GSZ (NBLK * NTHR) // 131072 threads

// Fully fused pipeline (one cooperative launch):
//  A: zero deg,s
//  B: deg[dst]++                       (E atomics, L2-resident 80KB)
//  C: s[src] += rsqrt(deg[dst]+1)      (E atomics)
//  D: per-block partial of v[b,k] = sum_n w(n)*combined[b,n,k]  (41MB stream)
//  E+F: blocks 0..3 reduce partials for batch b=blockIdx and run the MLP head
//       entirely in LDS/registers (v never touches HBM).
__global__ void __launch_bounds__(NTHR) fused_kernel(
    const float* __restrict__ fa, const float* __restrict__ fb,
    const int* __restrict__ src, const int* __restrict__ dst,
    const float* __restrict__ Wg, const float* __restrict__ bg,
    const float* __restrict__ W1, const float* __restrict__ b1,
    const float* __restrict__ W2, const float* __restrict__ b2,
    float* __restrict__ out,
    float* __restrict__ deg, float* __restrict__ s, float* __restrict__ partial)
{
    cg::grid_group grid = cg::this_grid();
    const int t = threadIdx.x;
    const int bk = blockIdx.x;
    const int gtid = bk * NTHR + t;

    // ---- Phase A: zero deg and s (contiguous: deg[NN], s[NN]) ----
    for (int i = gtid; i < 2 * NN; i += GSZ) deg[i] = 0.0f;
    grid.sync();

    // ---- Phase B: in-degree histogram ----
    for (int e = gtid; e < NE; e += GSZ) atomicAdd(&deg[dst[e]], 1.0f);
    grid.sync();

    // ---- Phase C: s[src] += dinv[dst] ----
    for (int e = gtid; e < NE; e += GSZ)
        atomicAdd(&s[src[e]], rsqrtf(deg[dst[e]] + 1.0f));
    grid.sync();

    // ---- Phase D: weighted feature sum -> per-block partials ----
    // 16 node-groups x 32 lanes; lane q<16 covers feat_a[.., q*4..q*4+3],
    // q>=16 covers feat_b. b-loop inner gives 4 independent loads in flight.
    {
        const int per = (NN + NBLK - 1) / NBLK;   // 79
        const int n0 = bk * per;
        const int n1 = min(NN, n0 + per);
        const int g = t >> 5;
        const int q = t & 31;
        const float* base = (q < 16) ? (fa + q * 4) : (fb + (q - 16) * 4);

        float4 acc[NB];
        #pragma unroll
        for (int b = 0; b < NB; ++b) acc[b] = make_float4(0.f, 0.f, 0.f, 0.f);

        for (int n = n0 + g; n < n1; n += 16) {
            float dinv = rsqrtf(deg[n] + 1.0f);
            float w = dinv * (dinv + s[n]);
            #pragma unroll
            for (int b = 0; b < NB; ++b) {
                float4 x = *reinterpret_cast<const float4*>(base + ((size_t)b * NN + n) * 64);
                acc[b].x += w * x.x; acc[b].y += w * x.y;
                acc[b].z += w * x.z; acc[b].w += w * x.w;
            }
        }

        __shared__ float4 smem[NTHR];
        #pragma unroll
        for (int b = 0; b < NB; ++b) {
            smem[t] = acc[b];
            __syncthreads();
            if (t < 32) {
                float4 r = smem[t];
                #pragma unroll
                for (int gg = 1; gg < 16; ++gg) {
                    float4 o = smem[gg * 32 + t];
                    r.x += o.x; r.y += o.y; r.z += o.z; r.w += o.w;
                }
                const int k = (t < 16) ? t * 4 : 64 + (t - 16) * 4;
                float* p = partial + (size_t)bk * (NB * HH) + b * HH + k;
                p[0] = r.x; p[1] = r.y; p[2] = r.z; p[3] = r.w;
            }
            __syncthreads();
        }
    }
    grid.sync();

    // ---- Phase E+F: blocks 0..3 finish batch b = bk ----
    if (bk < NB) {
        const int b = bk;
        __shared__ float xs[HH];
        __shared__ float ys[HH];
        __shared__ float red4[4][HH];
        const int k = t & (HH - 1);
        const int sl = t >> 7;   // slice 0..3

        // reduce partials over 256 blocks (64 rows per slice), coalesced
        float acc = 0.0f;
        #pragma unroll 16
        for (int r = sl; r < NBLK; r += 4)
            acc += partial[(size_t)r * (NB * HH) + b * HH + k];
        red4[sl][k] = acc;
        __syncthreads();
        if (t < HH)
            xs[t] = (red4[0][t] + red4[1][t] + red4[2][t] + red4[3][t]) * (1.0f / NN);
        __syncthreads();

        // layer 1: pooled = xs @ Wg + bg   (j sliced 4-way)
        float a1 = 0.0f;
        #pragma unroll 8
        for (int j = sl * 32; j < sl * 32 + 32; ++j) a1 += xs[j] * Wg[j * HH + k];
        red4[sl][k] = a1;
        __syncthreads();
        if (t < HH)
            ys[t] = bg[t] + red4[0][t] + red4[1][t] + red4[2][t] + red4[3][t];
        __syncthreads();

        // layer 2: hid = relu(ys @ W1 + b1), fold W2 scale
        float a2 = 0.0f;
        #pragma unroll 8
        for (int j = sl * 32; j < sl * 32 + 32; ++j) a2 += ys[j] * W1[j * HH + k];
        red4[sl][k] = a2;
        __syncthreads();
        if (t < HH) {
            float h = fmaxf(b1[t] + red4[0][t] + red4[1][t] + red4[2][t] + red4[3][t], 0.0f);
            xs[t] = h * W2[t];
        }
        __syncthreads();

        // tree-reduce xs[0..127] -> out[b]
        #pragma unroll
        for (int off = HH / 2; off > 0; off >>= 1) {
            if (t < off) xs[t] += xs[t + off];
            __syncthreads();
        }
        if (t == 0) out[b] = xs[0] + b2[0];
    }
}

extern "C" void kernel_launch(void* const* d_in, const int* in_sizes, int n_in,
                              void* d_out, int out_size, void* d_ws, size_t ws_size,
                              hipStream_t stream) {
    const float* fa = (const float*)d_in[0];   // [B,N,64]
    const float* fb = (const float*)d_in[1];   // [B,N,64]
    const int*   ei = (const int*)d_in[2];     // [2,E]
    const float* Wg = (const float*)d_in[3];   // [H,H]
    const float* bg = (const float*)d_in[4];   // [H]
    const float* W1 = (const float*)d_in[5];   // [H,H]
    const float* b1 = (const float*)d_in[6];   // [H]
    const float* W2 = (const float*)d_in[7];   // [H,1]
    const float* b2 = (const float*)d_in[8];   // [1]
    float* out = (float*)d_out;

    const int* src = ei;
    const int* dst = ei + NE;

    float* deg     = (float*)d_ws;     // NN floats
    float* s       = deg + NN;         // NN floats
    float* partial = s + NN;           // NBLK * NB * HH floats (512 KB)

    void* args[] = {
        (void*)&fa, (void*)&fb, (void*)&src, (void*)&dst,
        (void*)&Wg, (void*)&bg, (void*)&W1, (void*)&b1,
        (void*)&W2, (void*)&b2, (void*)&out,
        (void*)&deg, (void*)&s, (void*)&partial
    };
    hipLaunchCooperativeKernel((void*)fused_kernel, dim3(NBLK), dim3(NTHR),
                               args, 0, stream);
}